// Round 3
// baseline (410.346 us; speedup 1.0000x reference)
//
#include <hip/hip_runtime.h>
#include <math.h>

#define D_MODEL 256
#define NHEADS 8
#define HDIM 32
#define BATCH 8
#define SEQL 4096
#define EPS 1e-6f

typedef _Float16 f16;
typedef _Float16 f16x4 __attribute__((ext_vector_type(4)));
typedef _Float16 f16x8 __attribute__((ext_vector_type(8)));
typedef float f32x4 __attribute__((ext_vector_type(4)));

__device__ __forceinline__ float elu1(float x) {
    return x > 0.f ? x + 1.f : __expf(x);
}

// ---------------------------------------------------------------------------
// prep: convert 4 weight mats to fp16 (stage-1 rows permuted to head-major
// o' = h*32+kd; Wm columns permuted to match), permute stage-1 biases, and
// zero the KV/ksum accumulators (blocks 1025+).
// ---------------------------------------------------------------------------
__global__ void prep_kernel(const float* __restrict__ Wq, const float* __restrict__ Wk,
                            const float* __restrict__ Wv, const float* __restrict__ Wm,
                            const float* __restrict__ bq, const float* __restrict__ bk,
                            const float* __restrict__ bv,
                            f16* __restrict__ w16, float* __restrict__ bperm,
                            float* __restrict__ KVz) {
    const int bid = blockIdx.x;
    if (bid < 1024) {
        int idx = bid * 256 + threadIdx.x;
        int mat = idx >> 16, r = (idx >> 8) & 255, c = idx & 255;
        const float* W = (mat == 0) ? Wq : (mat == 1) ? Wk : (mat == 2) ? Wv : Wm;
        float v;
        if (mat < 3) v = W[(size_t)(((r & 31) << 3) + (r >> 5)) * 256 + c];
        else         v = W[(size_t)r * 256 + (((c & 31) << 3) + (c >> 5))];
        w16[idx] = (f16)v;
    } else if (bid == 1024) {
        int t = threadIdx.x;
        bperm[0 * 256 + t] = bq[((t & 31) << 3) + (t >> 5)];
        bperm[1 * 256 + t] = bk[((t & 31) << 3) + (t >> 5)];
        bperm[2 * 256 + t] = bv[((t & 31) << 3) + (t >> 5)];
    } else {
        int i = (bid - 1025) * 256 + threadIdx.x;  // 264 blocks * 256 = 67584
        KVz[i] = 0.f;
    }
}

// ---------------------------------------------------------------------------
// Fused stage-1 GEMM + KV/ksum.
// Per block (b, l-tile 128, m-tile 128ch = 4 heads): three sequential GEMM
// phases over K=256 input channels, phase order k, v, q (flat 24-iter loop,
// one barrier per iter, X prefetch issued post-barrier).
//  - k-phase epilogue: elu1(k'+bias) -> kT LDS tile (XOR-swizzled), ksum via
//    shfl-reduce + atomicAdd.  No global k write.
//  - v-phase epilogue: v'+bias -> vT LDS half-tiles (2 passes), per-wave
//    per-head 32x32 KV partial via 16x16x32 MFMA, atomicAdd to KV.
//    No global v write.
//  - q-phase epilogue: bias + fp16, bounce through LDS, store qp.
// kp/vp never materialized: saves ~133 MB of HBM traffic + the kv_kernel.
// LDS map (bytes): kT @0 (32768) [128ch][128l] f16 swz;
//   Bs0 @32768 (10240), Bs1 @43008 (10240)  [128l][40k] f16;
//   vT @32768 (16384, v-epilogue, aliases Bs) [128ch][64l] f16 swz;
//   Cb @32768 (18432, q-epilogue, aliases Bs).
// ---------------------------------------------------------------------------
#define BSTR 40
__global__ __launch_bounds__(256, 3) void gemm_fused(
    const float* __restrict__ Xq, const float* __restrict__ Xk, const float* __restrict__ Xv,
    const f16* __restrict__ w16, const float* __restrict__ bperm,
    f16* __restrict__ qp, float* __restrict__ KV, float* __restrict__ ksum) {
    __shared__ __align__(16) char smem[53248];
    f16* kT = (f16*)smem;                     // [128][128] + XOR((ch&7)<<4) on byte addr
    f16* B0 = (f16*)(smem + 32768);
    f16* B1 = (f16*)(smem + 43008);
    f16* vT = (f16*)(smem + 32768);           // [128][64] + XOR((ch&7)<<4)
    f16* Cb = (f16*)(smem + 32768);           // [128][72]

    const int b = blockIdx.z;
    const int l0 = blockIdx.x * 128;
    const int m0 = blockIdx.y * 128;
    const int tid = threadIdx.x;
    const int wave = tid >> 6, lane = tid & 63;
    const int wm = wave >> 1, wn = wave & 1;
    const int ln = lane & 15, quad = lane >> 4;
    const int g = tid >> 5;     // k-row group: rows 4g+r  (32 lanes/row -> 512B runs)
    const int bg = tid & 31;    // l group: cols 4*bg

    const float* Xarr[3] = {Xk, Xv, Xq};          // phase order k, v, q
    const int woff[3] = {65536, 131072, 0};       // w16 mat offsets: k, v, q
    const int boff[3] = {256, 512, 0};            // bperm offsets
    const size_t xoff = ((size_t)(b * D_MODEL) + 4 * g) * SEQL + l0 + 4 * bg;

    int wrow[4];
#pragma unroll
    for (int mf = 0; mf < 4; ++mf)
        wrow[mf] = (m0 + wm * 64 + mf * 16 + ln) * 256 + quad * 8;

    float4 xr[4];
    f16x8 afc[4], afn[4];

#define LOADX(PH, K0) do { \
        const float* xb_ = Xarr[PH] + xoff + (size_t)(K0) * SEQL; \
        xr[0] = *(const float4*)(xb_ + 0 * SEQL); \
        xr[1] = *(const float4*)(xb_ + 1 * SEQL); \
        xr[2] = *(const float4*)(xb_ + 2 * SEQL); \
        xr[3] = *(const float4*)(xb_ + 3 * SEQL); \
    } while (0)

#define STOREB(BUF) do { \
        f16x4 w_; \
        w_[0] = (f16)xr[0].x; w_[1] = (f16)xr[1].x; w_[2] = (f16)xr[2].x; w_[3] = (f16)xr[3].x; \
        *(f16x4*)&BUF[(4 * bg + 0) * BSTR + 4 * g] = w_; \
        w_[0] = (f16)xr[0].y; w_[1] = (f16)xr[1].y; w_[2] = (f16)xr[2].y; w_[3] = (f16)xr[3].y; \
        *(f16x4*)&BUF[(4 * bg + 1) * BSTR + 4 * g] = w_; \
        w_[0] = (f16)xr[0].z; w_[1] = (f16)xr[1].z; w_[2] = (f16)xr[2].z; w_[3] = (f16)xr[3].z; \
        *(f16x4*)&BUF[(4 * bg + 2) * BSTR + 4 * g] = w_; \
        w_[0] = (f16)xr[0].w; w_[1] = (f16)xr[1].w; w_[2] = (f16)xr[2].w; w_[3] = (f16)xr[3].w; \
        *(f16x4*)&BUF[(4 * bg + 3) * BSTR + 4 * g] = w_; \
    } while (0)

    f32x4 acc[4][4];
#pragma unroll
    for (int mf = 0; mf < 4; ++mf)
#pragma unroll
        for (int nf = 0; nf < 4; ++nf)
#pragma unroll
            for (int r = 0; r < 4; ++r) acc[mf][nf][r] = 0.f;

    // prologue: phase 0 (k), k0 = 0
    LOADX(0, 0);
#pragma unroll
    for (int mf = 0; mf < 4; ++mf) afc[mf] = *(const f16x8*)(w16 + woff[0] + wrow[mf]);

#pragma unroll
    for (int it = 0; it < 24; ++it) {
        const int k0 = (it & 7) * 32;
        f16* buf = (it & 1) ? B1 : B0;
        STOREB(buf);
        __syncthreads();
        if (it < 23) {
            const int phn = (it + 1) >> 3, k0n = ((it + 1) & 7) * 32;
            LOADX(phn, k0n);   // post-barrier issue: in flight across bf reads + MFMA
#pragma unroll
            for (int mf = 0; mf < 4; ++mf)
                afn[mf] = *(const f16x8*)(w16 + woff[phn] + wrow[mf] + k0n);
        }
        f16x8 bf[4];
#pragma unroll
        for (int nf = 0; nf < 4; ++nf)
            bf[nf] = *(const f16x8*)&buf[(wn * 64 + nf * 16 + ln) * BSTR + quad * 8];
#pragma unroll
        for (int mf = 0; mf < 4; ++mf)
#pragma unroll
            for (int nf = 0; nf < 4; ++nf)
                acc[mf][nf] = __builtin_amdgcn_mfma_f32_16x16x32_f16(afc[mf], bf[nf], acc[mf][nf], 0, 0, 0);
        if (it < 23) {
#pragma unroll
            for (int mf = 0; mf < 4; ++mf) afc[mf] = afn[mf];
        }

        // ---------------- k-phase epilogue ----------------
        if (it == 7) {
            const float* bpk = bperm + boff[0] + m0 + wm * 64;
            float sp[4][4];
#pragma unroll
            for (int mf = 0; mf < 4; ++mf)
#pragma unroll
                for (int r = 0; r < 4; ++r) {
                    const float bb = bpk[mf * 16 + quad * 4 + r];
                    const int o = wm * 64 + mf * 16 + quad * 4 + r;
                    float s = 0.f;
#pragma unroll
                    for (int nf = 0; nf < 4; ++nf) {
                        const int l = wn * 64 + nf * 16 + ln;
                        const float e = elu1(acc[mf][nf][r] + bb);
                        s += e;
                        *(f16*)((char*)kT + ((o * 256 + l * 2) ^ ((o & 7) << 4))) = (f16)e;
                    }
                    sp[mf][r] = s;
                }
#pragma unroll
            for (int st = 1; st < 16; st <<= 1)
#pragma unroll
                for (int mf = 0; mf < 4; ++mf)
#pragma unroll
                    for (int r = 0; r < 4; ++r)
                        sp[mf][r] += __shfl_xor(sp[mf][r], st);
            if (ln == 0) {
                float* kss = ksum + (size_t)b * 256 + m0 + wm * 64;
#pragma unroll
                for (int mf = 0; mf < 4; ++mf)
#pragma unroll
                    for (int r = 0; r < 4; ++r)
                        atomicAdd(&kss[mf * 16 + quad * 4 + r], sp[mf][r]);
            }
#pragma unroll
            for (int mf = 0; mf < 4; ++mf)
#pragma unroll
                for (int nf = 0; nf < 4; ++nf)
#pragma unroll
                    for (int r = 0; r < 4; ++r) acc[mf][nf][r] = 0.f;
        }

        // ---------------- v-phase epilogue: vT + KV MFMA ----------------
        if (it == 15) {
            const float* bpv = bperm + boff[1] + m0 + wm * 64;
#pragma unroll
            for (int mf = 0; mf < 4; ++mf)
#pragma unroll
                for (int r = 0; r < 4; ++r) {
                    const float bb = bpv[mf * 16 + quad * 4 + r];
#pragma unroll
                    for (int nf = 0; nf < 4; ++nf) acc[mf][nf][r] += bb;
                }
            f32x4 kvacc[2][2];
#pragma unroll
            for (int ti = 0; ti < 2; ++ti)
#pragma unroll
                for (int tj = 0; tj < 2; ++tj)
#pragma unroll
                    for (int r = 0; r < 4; ++r) kvacc[ti][tj][r] = 0.f;
            const int hloc = wave;   // wave -> local head
#pragma unroll
            for (int pass = 0; pass < 2; ++pass) {
                __syncthreads();     // Bs reads drained; vT region free
                if (wn == pass) {
#pragma unroll
                    for (int mf = 0; mf < 4; ++mf)
#pragma unroll
                        for (int nf = 0; nf < 4; ++nf)
#pragma unroll
                            for (int r = 0; r < 4; ++r) {
                                const int o = wm * 64 + mf * 16 + quad * 4 + r;
                                const int l = nf * 16 + ln;   // local within half
                                *(f16*)((char*)vT + ((o * 128 + l * 2) ^ ((o & 7) << 4))) = (f16)acc[mf][nf][r];
                            }
                }
                __syncthreads();
#pragma unroll
                for (int ks = 0; ks < 2; ++ks) {
                    f16x8 av[2], bv2[2];
#pragma unroll
                    for (int t2 = 0; t2 < 2; ++t2) {
                        const int row = hloc * 32 + t2 * 16 + ln;
                        av[t2]  = *(const f16x8*)((char*)kT +
                                    ((row * 256 + (pass * 64 + ks * 32 + quad * 8) * 2) ^ ((row & 7) << 4)));
                        bv2[t2] = *(const f16x8*)((char*)vT +
                                    ((row * 128 + (ks * 32 + quad * 8) * 2) ^ ((row & 7) << 4)));
                    }
#pragma unroll
                    for (int ti = 0; ti < 2; ++ti)
#pragma unroll
                        for (int tj = 0; tj < 2; ++tj)
                            kvacc[ti][tj] = __builtin_amdgcn_mfma_f32_16x16x32_f16(av[ti], bv2[tj], kvacc[ti][tj], 0, 0, 0);
                }
            }
            __syncthreads();   // vT reads drained before q-phase STOREB reuses Bs
            float* KVb = KV + ((size_t)(b * NHEADS) + (m0 >> 5) + hloc) * 1024;
#pragma unroll
            for (int ti = 0; ti < 2; ++ti)
#pragma unroll
                for (int tj = 0; tj < 2; ++tj)
#pragma unroll
                    for (int r = 0; r < 4; ++r) {
                        const int kd = ti * 16 + quad * 4 + r;
                        const int qd = tj * 16 + ln;
                        atomicAdd(&KVb[qd * 32 + kd], kvacc[ti][tj][r]);
                    }
#pragma unroll
            for (int mf = 0; mf < 4; ++mf)
#pragma unroll
                for (int nf = 0; nf < 4; ++nf)
#pragma unroll
                    for (int r = 0; r < 4; ++r) acc[mf][nf][r] = 0.f;
        }

        // ---------------- q-phase epilogue: qp store ----------------
        if (it == 23) {
            const float* bpq = bperm + boff[2] + m0 + wm * 64;
            float bv_[4][4];
#pragma unroll
            for (int mf = 0; mf < 4; ++mf)
#pragma unroll
                for (int r = 0; r < 4; ++r)
                    bv_[mf][r] = bpq[mf * 16 + quad * 4 + r];
#pragma unroll
            for (int pass = 0; pass < 2; ++pass) {
                __syncthreads();
                if (wm == pass) {
#pragma unroll
                    for (int mf = 0; mf < 4; ++mf)
#pragma unroll
                        for (int nf = 0; nf < 4; ++nf) {
                            const int olocal = mf * 16 + quad * 4;
                            const int llocal = wn * 64 + nf * 16 + ln;
                            f16x4 w;
#pragma unroll
                            for (int r = 0; r < 4; ++r) w[r] = (f16)(acc[mf][nf][r] + bv_[mf][r]);
                            *(f16x4*)&Cb[llocal * 72 + olocal] = w;
                        }
                }
                __syncthreads();
                const int l = tid >> 1, half = tid & 1;
                f16* yr = qp + ((size_t)(b * SEQL + l0 + l)) * 256 + m0 + pass * 64 + half * 32;
#pragma unroll
                for (int u = 0; u < 4; ++u)
                    *(f16x8*)(yr + u * 8) = *(const f16x8*)&Cb[l * 72 + half * 32 + u * 8];
            }
        }
    }
#undef LOADX
#undef STOREB
}

// ---------------------------------------------------------------------------
// Fused attention + output projection; phase2 Wm frags register ping-pong
// prefetched (L2 latency off the critical path).
// ---------------------------------------------------------------------------
__global__ __launch_bounds__(256) void attn_out_kernel(
    const f16* __restrict__ qp, const float* __restrict__ KV,
    const float* __restrict__ ksum, const f16* __restrict__ wm16,
    const float* __restrict__ bm, float* __restrict__ out) {
    __shared__ __align__(16) f16 xs[64 * 264];        // 33792 B
    __shared__ __align__(16) f16 Baug[8 * 48 * 40];   // 30720 B
    __shared__ float dens[8][64];                     // 2048 B
    const int b = blockIdx.y;
    const int l0 = blockIdx.x * 64;
    const int t = threadIdx.x;
    const int wave = t >> 6, lane = t & 63;
    const int ln = lane & 15, quad = lane >> 4;

    {
        const int h = t >> 5, qd = t & 31;
        const float* kvp = KV + ((size_t)(b * NHEADS + h) * HDIM + qd) * HDIM;
        f16* dst = &Baug[(h * 48 + qd) * 40];
#pragma unroll
        for (int i = 0; i < 32; i += 4) {
            float4 a = *(const float4*)(kvp + i);
            f16x4 w4;
            w4[0] = (f16)a.x; w4[1] = (f16)a.y; w4[2] = (f16)a.z; w4[3] = (f16)a.w;
            *(f16x4*)(dst + i) = w4;
        }
        Baug[(h * 48 + 32) * 40 + qd] = (f16)ksum[(size_t)(b * NHEADS + h) * HDIM + qd];
    }
    {
        const int row = t & 63, cg = t >> 6;
        const f16* qr = qp + ((size_t)(b * SEQL + l0 + row)) * 256 + cg * 64;
        f16* dst = &xs[row * 264 + cg * 64];
#pragma unroll
        for (int u = 0; u < 64; u += 8) {
            f16x8 v = *(const f16x8*)(qr + u);
            f16x8 w;
#pragma unroll
            for (int j = 0; j < 8; ++j) w[j] = (f16)elu1((float)v[j]);
            *(f16x8*)(dst + u) = w;
        }
    }
    __syncthreads();
#pragma unroll
    for (int hh = 0; hh < 2; ++hh) {
        const int h = wave * 2 + hh;
        f16x8 a_s[4], b_s[3];
#pragma unroll
        for (int mf = 0; mf < 4; ++mf)
            a_s[mf] = *(const f16x8*)&xs[(mf * 16 + ln) * 264 + h * 32 + quad * 8];
#pragma unroll
        for (int nf = 0; nf < 3; ++nf)
            b_s[nf] = *(const f16x8*)&Baug[(h * 48 + nf * 16 + ln) * 40 + quad * 8];
        f32x4 C[4][3];
#pragma unroll
        for (int mf = 0; mf < 4; ++mf)
#pragma unroll
            for (int nf = 0; nf < 3; ++nf) {
#pragma unroll
                for (int r = 0; r < 4; ++r) C[mf][nf][r] = 0.f;
                C[mf][nf] = __builtin_amdgcn_mfma_f32_16x16x32_f16(a_s[mf], b_s[nf], C[mf][nf], 0, 0, 0);
            }
        if (ln == 0) {
#pragma unroll
            for (int mf = 0; mf < 4; ++mf)
#pragma unroll
                for (int r = 0; r < 4; ++r)
                    dens[h][mf * 16 + quad * 4 + r] = C[mf][2][r];
        }
        __syncthreads();
#pragma unroll
        for (int mf = 0; mf < 4; ++mf)
#pragma unroll
            for (int r = 0; r < 4; ++r) {
                const int l = mf * 16 + quad * 4 + r;
                const float rd = __builtin_amdgcn_rcpf(dens[h][l] + EPS);
#pragma unroll
                for (int nf = 0; nf < 2; ++nf)
                    xs[l * 264 + h * 32 + nf * 16 + ln] = (f16)(C[mf][nf][r] * rd);
            }
        __syncthreads();
    }
    // phase2: main GEMM, A = Wm prefetched ping-pong from global, B = xs
    f32x4 acc[4][4];
#pragma unroll
    for (int mf = 0; mf < 4; ++mf)
#pragma unroll
        for (int nf = 0; nf < 4; ++nf)
#pragma unroll
            for (int r = 0; r < 4; ++r) acc[mf][nf][r] = 0.f;
    const f16* Wb[4];
#pragma unroll
    for (int mf = 0; mf < 4; ++mf)
        Wb[mf] = wm16 + (size_t)(wave * 64 + mf * 16 + ln) * 256 + quad * 8;
    f16x8 afc[4], afn[4];
#pragma unroll
    for (int mf = 0; mf < 4; ++mf) afc[mf] = *(const f16x8*)(Wb[mf] + 0);
#pragma unroll
    for (int it = 0; it < 8; ++it) {
        const int k0 = it * 32;
        if (it < 7) {
#pragma unroll
            for (int mf = 0; mf < 4; ++mf) afn[mf] = *(const f16x8*)(Wb[mf] + k0 + 32);
        }
        f16x8 bf[4];
#pragma unroll
        for (int nf = 0; nf < 4; ++nf)
            bf[nf] = *(const f16x8*)&xs[(nf * 16 + ln) * 264 + k0 + quad * 8];
#pragma unroll
        for (int mf = 0; mf < 4; ++mf)
#pragma unroll
            for (int nf = 0; nf < 4; ++nf)
                acc[mf][nf] = __builtin_amdgcn_mfma_f32_16x16x32_f16(afc[mf], bf[nf], acc[mf][nf], 0, 0, 0);
#pragma unroll
        for (int mf = 0; mf < 4; ++mf) afc[mf] = afn[mf];
    }
#pragma unroll
    for (int mf = 0; mf < 4; ++mf) {
        const int o = wave * 64 + mf * 16 + quad * 4;
#pragma unroll
        for (int r = 0; r < 4; ++r) {
            const float bb = bm[o + r];
            float* op = out + ((size_t)(b * D_MODEL + o + r)) * SEQL + l0;
#pragma unroll
            for (int nf = 0; nf < 4; ++nf)
                op[nf * 16 + ln] = acc[mf][nf][r] + bb;
        }
    }
}

// ---------------------------------------------------------------------------
extern "C" void kernel_launch(void* const* d_in, const int* in_sizes, int n_in,
                              void* d_out, int out_size, void* d_ws, size_t ws_size,
                              hipStream_t stream) {
    const float* query = (const float*)d_in[0];
    const float* key_  = (const float*)d_in[1];
    const float* value = (const float*)d_in[2];
    const float* Wq = (const float*)d_in[3];
    const float* bq = (const float*)d_in[4];
    const float* Wk = (const float*)d_in[5];
    const float* bk = (const float*)d_in[6];
    const float* Wv = (const float*)d_in[7];
    const float* bv = (const float*)d_in[8];
    const float* Wm = (const float*)d_in[9];
    const float* bm = (const float*)d_in[10];

    char* w = (char*)d_ws;
    f16*   w16   = (f16*)w;                       // 4*65536 halves = 512 KB
    float* bperm = (float*)(w + 524288);          // 768 floats
    float* KV    = (float*)(w + 528384);          // 65536 floats (+2048 ksum, zeroed together)
    float* ksum  = (float*)(w + 790528);          // 2048 floats
    f16*   qp    = (f16*)(w + 802816);

    prep_kernel<<<1289, 256, 0, stream>>>(Wq, Wk, Wv, Wm, bq, bk, bv, w16, bperm, KV);

    gemm_fused<<<dim3(SEQL / 128, 2, BATCH), 256, 0, stream>>>(
        query, key_, value, w16, bperm, qp, KV, ksum);

    attn_out_kernel<<<dim3(SEQL / 64, BATCH), 256, 0, stream>>>(
        qp, KV, ksum, w16 + 3 * 65536, bm, (float*)d_out);
}

// Round 4
// 232.370 us; speedup vs baseline: 1.7659x; 1.7659x over previous
//
#include <hip/hip_runtime.h>
#include <math.h>

#define D_MODEL 256
#define NHEADS 8
#define HDIM 32
#define BATCH 8
#define SEQL 4096
#define EPS 1e-6f

typedef _Float16 f16;
typedef _Float16 f16x4 __attribute__((ext_vector_type(4)));
typedef _Float16 f16x8 __attribute__((ext_vector_type(8)));
typedef float f32x4 __attribute__((ext_vector_type(4)));

__device__ __forceinline__ float elu1(float x) {
    return x > 0.f ? x + 1.f : __expf(x);
}

// ---------------------------------------------------------------------------
// prep: convert 4 weight mats to fp16 (stage-1 rows permuted to head-major
// o' = h*32+kd; Wm columns permuted to match), permute stage-1 biases.
// (KV zeroing dropped: kv_mfma writes full partials, no accumulation.)
// ---------------------------------------------------------------------------
__global__ void prep_kernel(const float* __restrict__ Wq, const float* __restrict__ Wk,
                            const float* __restrict__ Wv, const float* __restrict__ Wm,
                            const float* __restrict__ bq, const float* __restrict__ bk,
                            const float* __restrict__ bv,
                            f16* __restrict__ w16, float* __restrict__ bperm) {
    const int bid = blockIdx.x;
    if (bid < 1024) {
        int idx = bid * 256 + threadIdx.x;
        int mat = idx >> 16, r = (idx >> 8) & 255, c = idx & 255;
        const float* W = (mat == 0) ? Wq : (mat == 1) ? Wk : (mat == 2) ? Wv : Wm;
        float v;
        if (mat < 3) v = W[(size_t)(((r & 31) << 3) + (r >> 5)) * 256 + c];
        else         v = W[(size_t)r * 256 + (((c & 31) << 3) + (c >> 5))];
        w16[idx] = (f16)v;
    } else {
        int t = threadIdx.x;
        bperm[0 * 256 + t] = bq[((t & 31) << 3) + (t >> 5)];
        bperm[1 * 256 + t] = bk[((t & 31) << 3) + (t >> 5)];
        bperm[2 * 256 + t] = bv[((t & 31) << 3) + (t >> 5)];
    }
}

// ---------------------------------------------------------------------------
// Stage-1 GEMM (round-2 verified version): Y[b][l][o'] =
//   fp16( sum_i W16[o'][i] * X[b][i][l] + bperm[o'] )
// 128x128 tile, double-buffered Bs, one barrier per K-iter, X reg ping-pong.
// ---------------------------------------------------------------------------
#define BSTR 40
__global__ __launch_bounds__(256, 3) void gemm_stage1(
    const float* __restrict__ Xq, const float* __restrict__ Xk, const float* __restrict__ Xv,
    const f16* __restrict__ w16, const float* __restrict__ bperm,
    f16* __restrict__ yq, f16* __restrict__ yk, f16* __restrict__ yv) {
    __shared__ __align__(16) char smem[20480];
    f16* B0 = (f16*)smem;                 // [128][BSTR] = 10240 B
    f16* B1 = (f16*)smem + 128 * BSTR;    // [128][BSTR] = 10240 B
    f16* Cb = (f16*)smem;                 // [128][72] epilogue bounce (aliases B0/B1)

    const int z = blockIdx.z;
    const int which = z >> 3;
    const int b = z & 7;
    const float* X = (which == 0) ? Xq : (which == 1) ? Xk : Xv;
    const f16* W = w16 + which * 65536;
    f16* Y = (which == 0) ? yq : (which == 1) ? yk : yv;
    const float* bp = bperm + which * 256;

    const int l0 = blockIdx.x * 128;
    const int m0 = blockIdx.y * 128;
    const int tid = threadIdx.x;
    const int wave = tid >> 6, lane = tid & 63;
    const int wm = wave >> 1, wn = wave & 1;
    const int ln = lane & 15, quad = lane >> 4;
    const int bp8 = tid & 7;    // i-quad: i_local = 4*bp8 + r
    const int bg = tid >> 3;    // l-quad: l_local = 4*bg + j

    const float* Xbase = X + ((size_t)b * D_MODEL + 4 * bp8) * SEQL + l0 + 4 * bg;
    const f16* Wb[4];
#pragma unroll
    for (int mf = 0; mf < 4; ++mf)
        Wb[mf] = W + (size_t)(m0 + wm * 64 + mf * 16 + ln) * 256 + quad * 8;

    float4 xa[4], xb[4];
    f16x8 afc[4], afn[4];

#define LOADX(DST, K0) do { \
        const float* xb_ = Xbase + (size_t)(K0) * SEQL; \
        DST[0] = *(const float4*)(xb_ + 0 * SEQL); \
        DST[1] = *(const float4*)(xb_ + 1 * SEQL); \
        DST[2] = *(const float4*)(xb_ + 2 * SEQL); \
        DST[3] = *(const float4*)(xb_ + 3 * SEQL); \
    } while (0)

#define STOREB(SRC, BUF) do { \
        f16x4 w_; \
        w_[0] = (f16)SRC[0].x; w_[1] = (f16)SRC[1].x; w_[2] = (f16)SRC[2].x; w_[3] = (f16)SRC[3].x; \
        *(f16x4*)&BUF[(4 * bg + 0) * BSTR + 4 * bp8] = w_; \
        w_[0] = (f16)SRC[0].y; w_[1] = (f16)SRC[1].y; w_[2] = (f16)SRC[2].y; w_[3] = (f16)SRC[3].y; \
        *(f16x4*)&BUF[(4 * bg + 1) * BSTR + 4 * bp8] = w_; \
        w_[0] = (f16)SRC[0].z; w_[1] = (f16)SRC[1].z; w_[2] = (f16)SRC[2].z; w_[3] = (f16)SRC[3].z; \
        *(f16x4*)&BUF[(4 * bg + 2) * BSTR + 4 * bp8] = w_; \
        w_[0] = (f16)SRC[0].w; w_[1] = (f16)SRC[1].w; w_[2] = (f16)SRC[2].w; w_[3] = (f16)SRC[3].w; \
        *(f16x4*)&BUF[(4 * bg + 3) * BSTR + 4 * bp8] = w_; \
    } while (0)

    f32x4 acc[4][4];
#pragma unroll
    for (int mf = 0; mf < 4; ++mf)
#pragma unroll
        for (int nf = 0; nf < 4; ++nf)
#pragma unroll
            for (int r = 0; r < 4; ++r) acc[mf][nf][r] = 0.f;

    // prologue
    LOADX(xa, 0);
#pragma unroll
    for (int mf = 0; mf < 4; ++mf) afc[mf] = *(const f16x8*)(Wb[mf] + 0);

#pragma unroll
    for (int it = 0; it < 8; ++it) {
        const int k0 = it * 32;
        f16* buf = (it & 1) ? B1 : B0;
        if (it < 7) {
            if (it & 1) LOADX(xa, k0 + 32);
            else        LOADX(xb, k0 + 32);
        }
        if (it & 1) STOREB(xb, buf);
        else        STOREB(xa, buf);
        __syncthreads();
        if (it < 7) {
#pragma unroll
            for (int mf = 0; mf < 4; ++mf)
                afn[mf] = *(const f16x8*)(Wb[mf] + k0 + 32);
        }
        f16x8 bf[4];
#pragma unroll
        for (int nf = 0; nf < 4; ++nf)
            bf[nf] = *(const f16x8*)&buf[(wn * 64 + nf * 16 + ln) * BSTR + quad * 8];
#pragma unroll
        for (int mf = 0; mf < 4; ++mf)
#pragma unroll
            for (int nf = 0; nf < 4; ++nf)
                acc[mf][nf] = __builtin_amdgcn_mfma_f32_16x16x32_f16(afc[mf], bf[nf], acc[mf][nf], 0, 0, 0);
#pragma unroll
        for (int mf = 0; mf < 4; ++mf) afc[mf] = afn[mf];
    }

    // epilogue: bias, bounce through LDS as [l][o], coalesced fp16 store
    float bv_[4][4];
#pragma unroll
    for (int mf = 0; mf < 4; ++mf)
#pragma unroll
        for (int r = 0; r < 4; ++r)
            bv_[mf][r] = bp[m0 + wm * 64 + mf * 16 + quad * 4 + r];
#pragma unroll
    for (int pass = 0; pass < 2; ++pass) {
        __syncthreads();
        if (wm == pass) {
#pragma unroll
            for (int mf = 0; mf < 4; ++mf)
#pragma unroll
                for (int nf = 0; nf < 4; ++nf) {
                    const int olocal = mf * 16 + quad * 4;
                    const int llocal = wn * 64 + nf * 16 + ln;
                    f16x4 w;
#pragma unroll
                    for (int r = 0; r < 4; ++r) w[r] = (f16)(acc[mf][nf][r] + bv_[mf][r]);
                    *(f16x4*)&Cb[llocal * 72 + olocal] = w;
                }
        }
        __syncthreads();
        const int l = tid >> 1, half = tid & 1;
        f16* yr = Y + ((size_t)(b * SEQL + l0 + l)) * 256 + m0 + pass * 64 + half * 32;
#pragma unroll
        for (int u = 0; u < 4; ++u)
            *(f16x8*)(yr + u * 8) = *(const f16x8*)&Cb[l * 72 + half * 32 + u * 8];
    }
#undef LOADX
#undef STOREB
}

// ---------------------------------------------------------------------------
// kv_mfma: per (lsplit, b, h) block, KVpart[ls][bh][qd][kd] =
//   sum_{l in split} v'[l][qd] * elu1(k'[l][kd]);  ksum via augmented A-row
//   of ones (vT row 32).  MFMA 16x16x32, LDS-transposed staging, NO atomics.
// ---------------------------------------------------------------------------
#define KVLP 66   // padded LDS row stride (halves): +1-bank stagger on frags
__global__ __launch_bounds__(256) void kv_mfma(
    const f16* __restrict__ kp, const f16* __restrict__ vp,
    float* __restrict__ KVpart, float* __restrict__ ksum_part) {
    __shared__ __align__(16) f16 kT[32 * KVLP];   // [kd][l]  (elu applied)
    __shared__ __align__(16) f16 vT[48 * KVLP];   // [qd][l]; rows 32..47: ones-row aug
    const int ls = blockIdx.x;    // 0..7 (l split of 512)
    const int bh = blockIdx.y;    // 0..63
    const int b = bh >> 3, h = bh & 7;
    const int t = threadIdx.x;
    const int wave = t >> 6, lane = t & 63;
    const int ln = lane & 15, quad = lane >> 4;
    const int lrow = t >> 2, seg = t & 3;

    // augmented rows init (once): row 32 = 1.0, rows 33..47 = 0
    {
        const int rr = 32 + (t >> 4), c0 = (t & 15) * 4;
        f16x4 w;
        const f16 one = (f16)1.f, zero = (f16)0.f;
        w[0] = w[1] = w[2] = w[3] = (rr == 32) ? one : zero;
        *(f16x4*)&vT[rr * KVLP + c0] = w;
    }

    // wave tile map: primary (tiP,tjP) = (wave>>1, wave&1); waves 0,1 also own
    // the ksum tile (ti=2, tj=wave), sharing the B fragment with primary.
    const int tiP = wave >> 1, tjP = wave & 1;
    f32x4 accP, accS;
#pragma unroll
    for (int r = 0; r < 4; ++r) { accP[r] = 0.f; accS[r] = 0.f; }

    for (int ch = 0; ch < 8; ++ch) {
        __syncthreads();   // prev chunk's fragment reads done
        const size_t goff = ((size_t)(b * SEQL + ls * 512 + ch * 64 + lrow)) * 256 + h * 32 + seg * 8;
        f16x8 k8 = *(const f16x8*)(kp + goff);
        f16x8 v8 = *(const f16x8*)(vp + goff);
#pragma unroll
        for (int j = 0; j < 8; ++j) {
            kT[(seg * 8 + j) * KVLP + lrow] = (f16)elu1((float)k8[j]);
            vT[(seg * 8 + j) * KVLP + lrow] = v8[j];
        }
        __syncthreads();
#pragma unroll
        for (int ks = 0; ks < 2; ++ks) {
            const int kc = ks * 32 + quad * 8;
            f16x8 bP = *(const f16x8*)&kT[(tjP * 16 + ln) * KVLP + kc];
            f16x8 aP = *(const f16x8*)&vT[(tiP * 16 + ln) * KVLP + kc];
            accP = __builtin_amdgcn_mfma_f32_16x16x32_f16(aP, bP, accP, 0, 0, 0);
            if (wave < 2) {
                f16x8 aS = *(const f16x8*)&vT[(32 + ln) * KVLP + kc];
                accS = __builtin_amdgcn_mfma_f32_16x16x32_f16(aS, bP, accS, 0, 0, 0);
            }
        }
    }

    float* KVp = KVpart + ((size_t)ls * 64 + bh) * 1024;
#pragma unroll
    for (int r = 0; r < 4; ++r)
        KVp[(tiP * 16 + quad * 4 + r) * 32 + tjP * 16 + ln] = accP[r];
    if (wave < 2 && quad == 0)
        ksum_part[((size_t)ls * 64 + bh) * 32 + tjP * 16 + ln] = accS[0];
}

// ---------------------------------------------------------------------------
// Fused attention + output projection.  Baug staging now sums the 8 KV/ksum
// lsplit partials (L2-resident, plain loads).
// ---------------------------------------------------------------------------
__global__ __launch_bounds__(256) void attn_out_kernel(
    const f16* __restrict__ qp, const float* __restrict__ KVpart,
    const float* __restrict__ ksum_part, const f16* __restrict__ wm16,
    const float* __restrict__ bm, float* __restrict__ out) {
    __shared__ __align__(16) f16 xs[64 * 264];        // 33792 B
    __shared__ __align__(16) f16 Baug[8 * 48 * 40];   // 30720 B
    __shared__ float dens[8][64];                     // 2048 B
    const int b = blockIdx.y;
    const int l0 = blockIdx.x * 64;
    const int t = threadIdx.x;
    const int wave = t >> 6, lane = t & 63;
    const int ln = lane & 15, quad = lane >> 4;

    {
        const int h = t >> 5, qd = t & 31;
        const float* kvp = KVpart + (size_t)(b * NHEADS + h) * 1024 + qd * 32;
        f16* dst = &Baug[(h * 48 + qd) * 40];
#pragma unroll
        for (int i = 0; i < 32; i += 4) {
            float ax = 0.f, ay = 0.f, az = 0.f, aw = 0.f;
#pragma unroll
            for (int s = 0; s < 8; ++s) {
                float4 p = *(const float4*)(kvp + (size_t)s * 65536 + i);
                ax += p.x; ay += p.y; az += p.z; aw += p.w;
            }
            f16x4 w4;
            w4[0] = (f16)ax; w4[1] = (f16)ay; w4[2] = (f16)az; w4[3] = (f16)aw;
            *(f16x4*)(dst + i) = w4;
        }
        float ksv = 0.f;
#pragma unroll
        for (int s = 0; s < 8; ++s)
            ksv += ksum_part[((size_t)s * 64 + b * NHEADS + h) * 32 + qd];
        Baug[(h * 48 + 32) * 40 + qd] = (f16)ksv;
    }
    {
        const int row = t & 63, cg = t >> 6;
        const f16* qr = qp + ((size_t)(b * SEQL + l0 + row)) * 256 + cg * 64;
        f16* dst = &xs[row * 264 + cg * 64];
#pragma unroll
        for (int u = 0; u < 64; u += 8) {
            f16x8 v = *(const f16x8*)(qr + u);
            f16x8 w;
#pragma unroll
            for (int j = 0; j < 8; ++j) w[j] = (f16)elu1((float)v[j]);
            *(f16x8*)(dst + u) = w;
        }
    }
    __syncthreads();
#pragma unroll
    for (int hh = 0; hh < 2; ++hh) {
        const int h = wave * 2 + hh;
        f16x8 a_s[4], b_s[3];
#pragma unroll
        for (int mf = 0; mf < 4; ++mf)
            a_s[mf] = *(const f16x8*)&xs[(mf * 16 + ln) * 264 + h * 32 + quad * 8];
#pragma unroll
        for (int nf = 0; nf < 3; ++nf)
            b_s[nf] = *(const f16x8*)&Baug[(h * 48 + nf * 16 + ln) * 40 + quad * 8];
        f32x4 C[4][3];
#pragma unroll
        for (int mf = 0; mf < 4; ++mf)
#pragma unroll
            for (int nf = 0; nf < 3; ++nf) {
#pragma unroll
                for (int r = 0; r < 4; ++r) C[mf][nf][r] = 0.f;
                C[mf][nf] = __builtin_amdgcn_mfma_f32_16x16x32_f16(a_s[mf], b_s[nf], C[mf][nf], 0, 0, 0);
            }
        if (ln == 0) {
#pragma unroll
            for (int mf = 0; mf < 4; ++mf)
#pragma unroll
                for (int r = 0; r < 4; ++r)
                    dens[h][mf * 16 + quad * 4 + r] = C[mf][2][r];
        }
        __syncthreads();
#pragma unroll
        for (int mf = 0; mf < 4; ++mf)
#pragma unroll
            for (int r = 0; r < 4; ++r) {
                const int l = mf * 16 + quad * 4 + r;
                const float rd = __builtin_amdgcn_rcpf(dens[h][l] + EPS);
#pragma unroll
                for (int nf = 0; nf < 2; ++nf)
                    xs[l * 264 + h * 32 + nf * 16 + ln] = (f16)(C[mf][nf][r] * rd);
            }
        __syncthreads();
    }
    // phase2: main GEMM, A = Wm prefetched ping-pong from global, B = xs
    f32x4 acc[4][4];
#pragma unroll
    for (int mf = 0; mf < 4; ++mf)
#pragma unroll
        for (int nf = 0; nf < 4; ++nf)
#pragma unroll
            for (int r = 0; r < 4; ++r) acc[mf][nf][r] = 0.f;
    const f16* Wb[4];
#pragma unroll
    for (int mf = 0; mf < 4; ++mf)
        Wb[mf] = wm16 + (size_t)(wave * 64 + mf * 16 + ln) * 256 + quad * 8;
    f16x8 afc[4], afn[4];
#pragma unroll
    for (int mf = 0; mf < 4; ++mf) afc[mf] = *(const f16x8*)(Wb[mf] + 0);
#pragma unroll
    for (int it = 0; it < 8; ++it) {
        const int k0 = it * 32;
        if (it < 7) {
#pragma unroll
            for (int mf = 0; mf < 4; ++mf) afn[mf] = *(const f16x8*)(Wb[mf] + k0 + 32);
        }
        f16x8 bf[4];
#pragma unroll
        for (int nf = 0; nf < 4; ++nf)
            bf[nf] = *(const f16x8*)&xs[(nf * 16 + ln) * 264 + k0 + quad * 8];
#pragma unroll
        for (int mf = 0; mf < 4; ++mf)
#pragma unroll
            for (int nf = 0; nf < 4; ++nf)
                acc[mf][nf] = __builtin_amdgcn_mfma_f32_16x16x32_f16(afc[mf], bf[nf], acc[mf][nf], 0, 0, 0);
#pragma unroll
        for (int mf = 0; mf < 4; ++mf) afc[mf] = afn[mf];
    }
#pragma unroll
    for (int mf = 0; mf < 4; ++mf) {
        const int o = wave * 64 + mf * 16 + quad * 4;
#pragma unroll
        for (int r = 0; r < 4; ++r) {
            const float bb = bm[o + r];
            float* op = out + ((size_t)(b * D_MODEL + o + r)) * SEQL + l0;
#pragma unroll
            for (int nf = 0; nf < 4; ++nf)
                op[nf * 16 + ln] = acc[mf][nf][r] + bb;
        }
    }
}

// ---------------------------------------------------------------------------
extern "C" void kernel_launch(void* const* d_in, const int* in_sizes, int n_in,
                              void* d_out, int out_size, void* d_ws, size_t ws_size,
                              hipStream_t stream) {
    const float* query = (const float*)d_in[0];
    const float* key_  = (const float*)d_in[1];
    const float* value = (const float*)d_in[2];
    const float* Wq = (const float*)d_in[3];
    const float* bq = (const float*)d_in[4];
    const float* Wk = (const float*)d_in[5];
    const float* bk = (const float*)d_in[6];
    const float* Wv = (const float*)d_in[7];
    const float* bv = (const float*)d_in[8];
    const float* Wm = (const float*)d_in[9];
    const float* bm = (const float*)d_in[10];

    char* w = (char*)d_ws;
    f16*   w16    = (f16*)w;                        // 4*65536 halves = 524288 B
    float* bperm  = (float*)(w + 524288);           // 768 floats = 3072 B
    float* KVpart = (float*)(w + 528384);           // 8*64*1024 floats = 2 MB
    float* ksum_p = (float*)(w + 2625536);          // 8*64*32 floats = 64 KB
    f16*   qp     = (f16*)(w + 2691072);            // 16.7 MB each
    f16*   kp     = qp + (size_t)BATCH * SEQL * 256;
    f16*   vp     = kp + (size_t)BATCH * SEQL * 256;

    prep_kernel<<<1025, 256, 0, stream>>>(Wq, Wk, Wv, Wm, bq, bk, bv, w16, bperm);

    gemm_stage1<<<dim3(SEQL / 128, 2, 24), 256, 0, stream>>>(
        query, key_, value, w16, bperm, qp, kp, vp);

    kv_mfma<<<dim3(8, BATCH * NHEADS), 256, 0, stream>>>(kp, vp, KVpart, ksum_p);

    attn_out_kernel<<<dim3(SEQL / 64, BATCH), 256, 0, stream>>>(
        qp, KVpart, ksum_p, w16 + 3 * 65536, bm, (float*)d_out);
}

// Round 6
// 213.155 us; speedup vs baseline: 1.9251x; 1.0901x over previous
//
#include <hip/hip_runtime.h>
#include <math.h>

#define D_MODEL 256
#define NHEADS 8
#define HDIM 32
#define BATCH 8
#define SEQL 4096
#define EPS 1e-6f

typedef _Float16 f16;
typedef _Float16 f16x4 __attribute__((ext_vector_type(4)));
typedef _Float16 f16x8 __attribute__((ext_vector_type(8)));
typedef float f32x4 __attribute__((ext_vector_type(4)));

__device__ __forceinline__ float elu1(float x) {
    return x > 0.f ? x + 1.f : __expf(x);
}

// ---------------------------------------------------------------------------
// prep: convert 4 weight mats to fp16 (stage-1 rows permuted to head-major
// o' = h*32+kd; Wm columns permuted to match), permute stage-1 biases.
// ---------------------------------------------------------------------------
__global__ void prep_kernel(const float* __restrict__ Wq, const float* __restrict__ Wk,
                            const float* __restrict__ Wv, const float* __restrict__ Wm,
                            const float* __restrict__ bq, const float* __restrict__ bk,
                            const float* __restrict__ bv,
                            f16* __restrict__ w16, float* __restrict__ bperm) {
    const int bid = blockIdx.x;
    if (bid < 1024) {
        int idx = bid * 256 + threadIdx.x;
        int mat = idx >> 16, r = (idx >> 8) & 255, c = idx & 255;
        const float* W = (mat == 0) ? Wq : (mat == 1) ? Wk : (mat == 2) ? Wv : Wm;
        float v;
        if (mat < 3) v = W[(size_t)(((r & 31) << 3) + (r >> 5)) * 256 + c];
        else         v = W[(size_t)r * 256 + (((c & 31) << 3) + (c >> 5))];
        w16[idx] = (f16)v;
    } else {
        int t = threadIdx.x;
        bperm[0 * 256 + t] = bq[((t & 31) << 3) + (t >> 5)];
        bperm[1 * 256 + t] = bk[((t & 31) << 3) + (t >> 5)];
        bperm[2 * 256 + t] = bv[((t & 31) << 3) + (t >> 5)];
    }
}

// ---------------------------------------------------------------------------
// Stage-1 GEMM v2: stage-once / one-barrier structure.
// Block = (which, b, 64-l slice).  Whole K=256 x l=64 X slab staged to LDS
// once (f16, rows l, k-contiguous, stride 264), 2-chunk register ping-pong,
// NO barriers during staging (threads write only rows they loaded).  One
// __syncthreads, then 8 k-steps x 16 MFMA per wave with zero barriers (wave
// w owns o-strip w*64; full o=256 per block => X fetched exactly once, no
// m-tile re-read).  Epilogue bounces through Cb (aliases dead Xs): 2 barriers.
// Barriers/block: 3 (was 12).
// ---------------------------------------------------------------------------
#define XSTR 264
__global__ __launch_bounds__(256, 3) void gemm_stage1(
    const float* __restrict__ Xq, const float* __restrict__ Xk, const float* __restrict__ Xv,
    const f16* __restrict__ w16, const float* __restrict__ bperm,
    f16* __restrict__ yq, f16* __restrict__ yk, f16* __restrict__ yv) {
    __shared__ __align__(16) f16 Xs[64 * XSTR];   // 33792 B
    f16* Cb = Xs;                                  // epilogue alias (Xs dead)

    const int z = blockIdx.z;
    const int which = z >> 3;
    const int b = z & 7;
    const float* X = (which == 0) ? Xq : (which == 1) ? Xk : Xv;
    const f16* W = w16 + which * 65536;
    f16* Y = (which == 0) ? yq : (which == 1) ? yk : yv;
    const float* bp = bperm + which * 256;

    const int l0 = blockIdx.x * 64;
    const int tid = threadIdx.x;
    const int wave = tid >> 6, lane = tid & 63;
    const int ln = lane & 15, quad = lane >> 4;
    const int kq = tid & 15;    // chunk-k: k = 64c + 4*kq + r
    const int lg = tid >> 4;    // l: 4*lg + j  (lg 0..15)

    const float* Xbase = X + ((size_t)(b * D_MODEL) + 4 * kq) * SEQL + l0 + 4 * lg;

    float4 xa[4], xb[4];

#define LOADX(DST, C) do { \
        const float* xp_ = Xbase + (size_t)(64 * (C)) * SEQL; \
        DST[0] = *(const float4*)(xp_ + 0 * SEQL); \
        DST[1] = *(const float4*)(xp_ + 1 * SEQL); \
        DST[2] = *(const float4*)(xp_ + 2 * SEQL); \
        DST[3] = *(const float4*)(xp_ + 3 * SEQL); \
    } while (0)

#define STOREB(SRC, C) do { \
        f16x4 w_; \
        w_[0] = (f16)SRC[0].x; w_[1] = (f16)SRC[1].x; w_[2] = (f16)SRC[2].x; w_[3] = (f16)SRC[3].x; \
        *(f16x4*)&Xs[(4 * lg + 0) * XSTR + 64 * (C) + 4 * kq] = w_; \
        w_[0] = (f16)SRC[0].y; w_[1] = (f16)SRC[1].y; w_[2] = (f16)SRC[2].y; w_[3] = (f16)SRC[3].y; \
        *(f16x4*)&Xs[(4 * lg + 1) * XSTR + 64 * (C) + 4 * kq] = w_; \
        w_[0] = (f16)SRC[0].z; w_[1] = (f16)SRC[1].z; w_[2] = (f16)SRC[2].z; w_[3] = (f16)SRC[3].z; \
        *(f16x4*)&Xs[(4 * lg + 2) * XSTR + 64 * (C) + 4 * kq] = w_; \
        w_[0] = (f16)SRC[0].w; w_[1] = (f16)SRC[1].w; w_[2] = (f16)SRC[2].w; w_[3] = (f16)SRC[3].w; \
        *(f16x4*)&Xs[(4 * lg + 3) * XSTR + 64 * (C) + 4 * kq] = w_; \
    } while (0)

    f32x4 acc[4][4];
#pragma unroll
    for (int mf = 0; mf < 4; ++mf)
#pragma unroll
        for (int nf = 0; nf < 4; ++nf)
#pragma unroll
            for (int r = 0; r < 4; ++r) acc[mf][nf][r] = 0.f;

    // staging: 4 chunks of 64 k, 2-deep prefetch, no barriers
    LOADX(xa, 0);
    LOADX(xb, 1);
    STOREB(xa, 0);
    LOADX(xa, 2);
    STOREB(xb, 1);
    LOADX(xb, 3);
    STOREB(xa, 2);
    STOREB(xb, 3);
    __syncthreads();   // the only pre-compute barrier

    // compute: wave owns o-strip wave*64, 8 k-steps, no barriers
    const f16* Wb[4];
#pragma unroll
    for (int mf = 0; mf < 4; ++mf)
        Wb[mf] = W + (size_t)(wave * 64 + mf * 16 + ln) * 256 + quad * 8;
    f16x8 afc[4], afn[4];
#pragma unroll
    for (int mf = 0; mf < 4; ++mf) afc[mf] = *(const f16x8*)(Wb[mf] + 0);
#pragma unroll
    for (int s = 0; s < 8; ++s) {
        const int k0 = s * 32;
        if (s < 7) {
#pragma unroll
            for (int mf = 0; mf < 4; ++mf)
                afn[mf] = *(const f16x8*)(Wb[mf] + k0 + 32);
        }
        f16x8 bf[4];
#pragma unroll
        for (int nf = 0; nf < 4; ++nf)
            bf[nf] = *(const f16x8*)&Xs[(nf * 16 + ln) * XSTR + k0 + quad * 8];
#pragma unroll
        for (int mf = 0; mf < 4; ++mf)
#pragma unroll
            for (int nf = 0; nf < 4; ++nf)
                acc[mf][nf] = __builtin_amdgcn_mfma_f32_16x16x32_f16(afc[mf], bf[nf], acc[mf][nf], 0, 0, 0);
#pragma unroll
        for (int mf = 0; mf < 4; ++mf) afc[mf] = afn[mf];
    }

    // epilogue: bias, bounce through Cb as [l][o], coalesced fp16 store
    float bv_[4][4];
#pragma unroll
    for (int mf = 0; mf < 4; ++mf)
#pragma unroll
        for (int r = 0; r < 4; ++r)
            bv_[mf][r] = bp[wave * 64 + mf * 16 + quad * 4 + r];
    __syncthreads();   // all Xs fragment reads complete
#pragma unroll
    for (int mf = 0; mf < 4; ++mf)
#pragma unroll
        for (int nf = 0; nf < 4; ++nf) {
            f16x4 w;
#pragma unroll
            for (int r = 0; r < 4; ++r) w[r] = (f16)(acc[mf][nf][r] + bv_[mf][r]);
            *(f16x4*)&Cb[(nf * 16 + ln) * XSTR + wave * 64 + mf * 16 + quad * 4] = w;
        }
    __syncthreads();
    {
        const int l = tid >> 2, sg = tid & 3;
        f16* yr = Y + ((size_t)(b * SEQL + l0 + l)) * 256 + sg * 64;
#pragma unroll
        for (int u = 0; u < 8; ++u)
            *(f16x8*)(yr + u * 8) = *(const f16x8*)&Cb[l * XSTR + sg * 64 + u * 8];
    }
#undef LOADX
#undef STOREB
}

// ---------------------------------------------------------------------------
// kv_mfma: per (lsplit, b, h) block, KVpart[ls][bh][qd][kd] =
//   sum_{l in split} v'[l][qd] * elu1(k'[l][kd]);  ksum via augmented A-row
//   of ones (vT row 32).  MFMA 16x16x32, LDS-transposed staging, NO atomics.
// ---------------------------------------------------------------------------
#define KVLP 66
__global__ __launch_bounds__(256) void kv_mfma(
    const f16* __restrict__ kp, const f16* __restrict__ vp,
    float* __restrict__ KVpart, float* __restrict__ ksum_part) {
    __shared__ __align__(16) f16 kT[32 * KVLP];   // [kd][l]  (elu applied)
    __shared__ __align__(16) f16 vT[48 * KVLP];   // [qd][l]; rows 32..47: ones-row aug
    const int ls = blockIdx.x;    // 0..7 (l split of 512)
    const int bh = blockIdx.y;    // 0..63
    const int b = bh >> 3, h = bh & 7;
    const int t = threadIdx.x;
    const int wave = t >> 6, lane = t & 63;
    const int ln = lane & 15, quad = lane >> 4;
    const int lrow = t >> 2, seg = t & 3;

    {
        const int rr = 32 + (t >> 4), c0 = (t & 15) * 4;
        f16x4 w;
        const f16 one = (f16)1.f, zero = (f16)0.f;
        w[0] = w[1] = w[2] = w[3] = (rr == 32) ? one : zero;
        *(f16x4*)&vT[rr * KVLP + c0] = w;
    }

    const int tiP = wave >> 1, tjP = wave & 1;
    f32x4 accP, accS;
#pragma unroll
    for (int r = 0; r < 4; ++r) { accP[r] = 0.f; accS[r] = 0.f; }

    for (int ch = 0; ch < 8; ++ch) {
        __syncthreads();
        const size_t goff = ((size_t)(b * SEQL + ls * 512 + ch * 64 + lrow)) * 256 + h * 32 + seg * 8;
        f16x8 k8 = *(const f16x8*)(kp + goff);
        f16x8 v8 = *(const f16x8*)(vp + goff);
#pragma unroll
        for (int j = 0; j < 8; ++j) {
            kT[(seg * 8 + j) * KVLP + lrow] = (f16)elu1((float)k8[j]);
            vT[(seg * 8 + j) * KVLP + lrow] = v8[j];
        }
        __syncthreads();
#pragma unroll
        for (int ks = 0; ks < 2; ++ks) {
            const int kc = ks * 32 + quad * 8;
            f16x8 bP = *(const f16x8*)&kT[(tjP * 16 + ln) * KVLP + kc];
            f16x8 aP = *(const f16x8*)&vT[(tiP * 16 + ln) * KVLP + kc];
            accP = __builtin_amdgcn_mfma_f32_16x16x32_f16(aP, bP, accP, 0, 0, 0);
            if (wave < 2) {
                f16x8 aS = *(const f16x8*)&vT[(32 + ln) * KVLP + kc];
                accS = __builtin_amdgcn_mfma_f32_16x16x32_f16(aS, bP, accS, 0, 0, 0);
            }
        }
    }

    float* KVp = KVpart + ((size_t)ls * 64 + bh) * 1024;
#pragma unroll
    for (int r = 0; r < 4; ++r)
        KVp[(tiP * 16 + quad * 4 + r) * 32 + tjP * 16 + ln] = accP[r];
    if (wave < 2 && quad == 0)
        ksum_part[((size_t)ls * 64 + bh) * 32 + tjP * 16 + ln] = accS[0];
}

// ---------------------------------------------------------------------------
// kv_reduce: sum the 8 lsplit partials -> final KV [bh][qd][kd], ksum [bh][kd]
// ---------------------------------------------------------------------------
__global__ __launch_bounds__(256) void kv_reduce(
    const float* __restrict__ KVpart, const float* __restrict__ ksum_part,
    float* __restrict__ KVfin, float* __restrict__ ksum_f) {
    const int bh = blockIdx.x;
    const int t = threadIdx.x;
    const float* src = KVpart + (size_t)bh * 1024 + t * 4;
    float ax = 0.f, ay = 0.f, az = 0.f, aw = 0.f;
#pragma unroll
    for (int s = 0; s < 8; ++s) {
        float4 p = *(const float4*)(src + (size_t)s * 65536);
        ax += p.x; ay += p.y; az += p.z; aw += p.w;
    }
    float4 o; o.x = ax; o.y = ay; o.z = az; o.w = aw;
    *(float4*)(KVfin + (size_t)bh * 1024 + t * 4) = o;
    if (t < 32) {
        float ss = 0.f;
#pragma unroll
        for (int s = 0; s < 8; ++s)
            ss += ksum_part[((size_t)s * 64 + bh) * 32 + t];
        ksum_f[bh * 32 + t] = ss;
    }
}

// ---------------------------------------------------------------------------
// Fused attention + output projection (round-2 form: direct KV/ksum reads).
// ---------------------------------------------------------------------------
__global__ __launch_bounds__(256) void attn_out_kernel(
    const f16* __restrict__ qp, const float* __restrict__ KV,
    const float* __restrict__ ksum, const f16* __restrict__ wm16,
    const float* __restrict__ bm, float* __restrict__ out) {
    __shared__ __align__(16) f16 xs[64 * 264];        // 33792 B
    __shared__ __align__(16) f16 Baug[8 * 48 * 40];   // 30720 B
    __shared__ float dens[8][64];                     // 2048 B
    const int b = blockIdx.y;
    const int l0 = blockIdx.x * 64;
    const int t = threadIdx.x;
    const int wave = t >> 6, lane = t & 63;
    const int ln = lane & 15, quad = lane >> 4;

    {
        const int h = t >> 5, qd = t & 31;
        const float* kvp = KV + ((size_t)(b * NHEADS + h) * HDIM + qd) * HDIM;
        f16* dst = &Baug[(h * 48 + qd) * 40];
#pragma unroll
        for (int i = 0; i < 32; i += 4) {
            float4 a = *(const float4*)(kvp + i);
            f16x4 w4;
            w4[0] = (f16)a.x; w4[1] = (f16)a.y; w4[2] = (f16)a.z; w4[3] = (f16)a.w;
            *(f16x4*)(dst + i) = w4;
        }
        Baug[(h * 48 + 32) * 40 + qd] = (f16)ksum[(size_t)(b * NHEADS + h) * HDIM + qd];
    }
    {
        const int row = t & 63, cg = t >> 6;
        const f16* qr = qp + ((size_t)(b * SEQL + l0 + row)) * 256 + cg * 64;
        f16* dst = &xs[row * 264 + cg * 64];
#pragma unroll
        for (int u = 0; u < 64; u += 8) {
            f16x8 v = *(const f16x8*)(qr + u);
            f16x8 w;
#pragma unroll
            for (int j = 0; j < 8; ++j) w[j] = (f16)elu1((float)v[j]);
            *(f16x8*)(dst + u) = w;
        }
    }
    __syncthreads();
#pragma unroll
    for (int hh = 0; hh < 2; ++hh) {
        const int h = wave * 2 + hh;
        f16x8 a_s[4], b_s[3];
#pragma unroll
        for (int mf = 0; mf < 4; ++mf)
            a_s[mf] = *(const f16x8*)&xs[(mf * 16 + ln) * 264 + h * 32 + quad * 8];
#pragma unroll
        for (int nf = 0; nf < 3; ++nf)
            b_s[nf] = *(const f16x8*)&Baug[(h * 48 + nf * 16 + ln) * 40 + quad * 8];
        f32x4 C[4][3];
#pragma unroll
        for (int mf = 0; mf < 4; ++mf)
#pragma unroll
            for (int nf = 0; nf < 3; ++nf) {
#pragma unroll
                for (int r = 0; r < 4; ++r) C[mf][nf][r] = 0.f;
                C[mf][nf] = __builtin_amdgcn_mfma_f32_16x16x32_f16(a_s[mf], b_s[nf], C[mf][nf], 0, 0, 0);
            }
        if (ln == 0) {
#pragma unroll
            for (int mf = 0; mf < 4; ++mf)
#pragma unroll
                for (int r = 0; r < 4; ++r)
                    dens[h][mf * 16 + quad * 4 + r] = C[mf][2][r];
        }
        __syncthreads();
#pragma unroll
        for (int mf = 0; mf < 4; ++mf)
#pragma unroll
            for (int r = 0; r < 4; ++r) {
                const int l = mf * 16 + quad * 4 + r;
                const float rd = __builtin_amdgcn_rcpf(dens[h][l] + EPS);
#pragma unroll
                for (int nf = 0; nf < 2; ++nf)
                    xs[l * 264 + h * 32 + nf * 16 + ln] = (f16)(C[mf][nf][r] * rd);
            }
        __syncthreads();
    }
    // phase2: main GEMM, A = Wm prefetched ping-pong from global, B = xs
    f32x4 acc[4][4];
#pragma unroll
    for (int mf = 0; mf < 4; ++mf)
#pragma unroll
        for (int nf = 0; nf < 4; ++nf)
#pragma unroll
            for (int r = 0; r < 4; ++r) acc[mf][nf][r] = 0.f;
    const f16* Wb[4];
#pragma unroll
    for (int mf = 0; mf < 4; ++mf)
        Wb[mf] = wm16 + (size_t)(wave * 64 + mf * 16 + ln) * 256 + quad * 8;
    f16x8 afc[4], afn[4];
#pragma unroll
    for (int mf = 0; mf < 4; ++mf) afc[mf] = *(const f16x8*)(Wb[mf] + 0);
#pragma unroll
    for (int it = 0; it < 8; ++it) {
        const int k0 = it * 32;
        if (it < 7) {
#pragma unroll
            for (int mf = 0; mf < 4; ++mf) afn[mf] = *(const f16x8*)(Wb[mf] + k0 + 32);
        }
        f16x8 bf[4];
#pragma unroll
        for (int nf = 0; nf < 4; ++nf)
            bf[nf] = *(const f16x8*)&xs[(nf * 16 + ln) * 264 + k0 + quad * 8];
#pragma unroll
        for (int mf = 0; mf < 4; ++mf)
#pragma unroll
            for (int nf = 0; nf < 4; ++nf)
                acc[mf][nf] = __builtin_amdgcn_mfma_f32_16x16x32_f16(afc[mf], bf[nf], acc[mf][nf], 0, 0, 0);
#pragma unroll
        for (int mf = 0; mf < 4; ++mf) afc[mf] = afn[mf];
    }
#pragma unroll
    for (int mf = 0; mf < 4; ++mf) {
        const int o = wave * 64 + mf * 16 + quad * 4;
#pragma unroll
        for (int r = 0; r < 4; ++r) {
            const float bb = bm[o + r];
            float* op = out + ((size_t)(b * D_MODEL + o + r)) * SEQL + l0;
#pragma unroll
            for (int nf = 0; nf < 4; ++nf)
                op[nf * 16 + ln] = acc[mf][nf][r] + bb;
        }
    }
}

// ---------------------------------------------------------------------------
extern "C" void kernel_launch(void* const* d_in, const int* in_sizes, int n_in,
                              void* d_out, int out_size, void* d_ws, size_t ws_size,
                              hipStream_t stream) {
    const float* query = (const float*)d_in[0];
    const float* key_  = (const float*)d_in[1];
    const float* value = (const float*)d_in[2];
    const float* Wq = (const float*)d_in[3];
    const float* bq = (const float*)d_in[4];
    const float* Wk = (const float*)d_in[5];
    const float* bk = (const float*)d_in[6];
    const float* Wv = (const float*)d_in[7];
    const float* bv = (const float*)d_in[8];
    const float* Wm = (const float*)d_in[9];
    const float* bm = (const float*)d_in[10];

    char* w = (char*)d_ws;
    f16*   w16    = (f16*)w;                        // 524288 B
    float* bperm  = (float*)(w + 524288);           // 3072 B
    float* KVpart = (float*)(w + 528384);           // 2097152 B
    float* ksum_p = (float*)(w + 2625536);          // 65536 B
    float* KVfin  = (float*)(w + 2691072);          // 262144 B
    float* ksum_f = (float*)(w + 2953216);          // 8192 B
    f16*   qp     = (f16*)(w + 2961408);            // 16.7 MB each
    f16*   kp     = qp + (size_t)BATCH * SEQL * 256;
    f16*   vp     = kp + (size_t)BATCH * SEQL * 256;

    prep_kernel<<<1025, 256, 0, stream>>>(Wq, Wk, Wv, Wm, bq, bk, bv, w16, bperm);

    gemm_stage1<<<dim3(SEQL / 64, 1, 24), 256, 0, stream>>>(
        query, key_, value, w16, bperm, qp, kp, vp);

    kv_mfma<<<dim3(8, BATCH * NHEADS), 256, 0, stream>>>(kp, vp, KVpart, ksum_p);

    kv_reduce<<<dim3(BATCH * NHEADS), 256, 0, stream>>>(KVpart, ksum_p, KVfin, ksum_f);

    attn_out_kernel<<<dim3(SEQL / 64, BATCH), 256, 0, stream>>>(
        qp, KVfin, ksum_f, w16 + 3 * 65536, bm, (float*)d_out);
}

// Round 7
// 199.397 us; speedup vs baseline: 2.0579x; 1.0690x over previous
//
#include <hip/hip_runtime.h>
#include <math.h>

#define D_MODEL 256
#define NHEADS 8
#define HDIM 32
#define BATCH 8
#define SEQL 4096
#define EPS 1e-6f

typedef _Float16 f16;
typedef _Float16 f16x4 __attribute__((ext_vector_type(4)));
typedef _Float16 f16x8 __attribute__((ext_vector_type(8)));
typedef float f32x4 __attribute__((ext_vector_type(4)));

__device__ __forceinline__ float elu1(float x) {
    return x > 0.f ? x + 1.f : __expf(x);
}

// ---------------------------------------------------------------------------
// prep v3: weights to fp16 in FRAGMENT-LINEAR (wfrag) layout so every MFMA
// A-fragment load is one contiguous 1 KB wave read (8 full cache lines
// instead of 16 half-used ones).  Logical W for mats 0-2 (q,k,v) is
// row-permuted to head-major o' = h*32+d; mat 3 (Wm) is column-permuted.
//   wfrag index: (((ostrip*8 + kstep)*64 + lane)*8 + e)
//   o = ostrip*16 + (lane&15);  k = kstep*32 + (lane>>4)*8 + e
// ---------------------------------------------------------------------------
__global__ void prep_kernel(const float* __restrict__ Wq, const float* __restrict__ Wk,
                            const float* __restrict__ Wv, const float* __restrict__ Wm,
                            const float* __restrict__ bq, const float* __restrict__ bk,
                            const float* __restrict__ bv,
                            f16* __restrict__ w16, float* __restrict__ bperm) {
    const int bid = blockIdx.x;
    if (bid < 1024) {
        int idx = bid * 256 + threadIdx.x;
        int mat = idx >> 16;
        int r = idx & 65535;
        int e = r & 7;
        int lane = (r >> 3) & 63;
        int kstep = (r >> 9) & 7;
        int ostrip = r >> 12;
        int o = ostrip * 16 + (lane & 15);
        int k = kstep * 32 + (lane >> 4) * 8 + e;
        const float* W = (mat == 0) ? Wq : (mat == 1) ? Wk : (mat == 2) ? Wv : Wm;
        float v;
        if (mat < 3) v = W[(size_t)(((o & 31) << 3) + (o >> 5)) * 256 + k];
        else         v = W[(size_t)o * 256 + (((k & 31) << 3) + (k >> 5))];
        w16[idx] = (f16)v;
    } else {
        int t = threadIdx.x;
        bperm[0 * 256 + t] = bq[((t & 31) << 3) + (t >> 5)];
        bperm[1 * 256 + t] = bk[((t & 31) << 3) + (t >> 5)];
        bperm[2 * 256 + t] = bv[((t & 31) << 3) + (t >> 5)];
    }
}

// ---------------------------------------------------------------------------
// Stage-1 GEMM v3: round-6 stage-once structure + wfrag W loads (coalesced).
// Block = (which, b, 64-l slice); whole K=256 x l=64 X slab staged to LDS
// once; one pre-compute barrier; wave owns o-strip wave*64; X fetched once.
// ---------------------------------------------------------------------------
#define XSTR 264
__global__ __launch_bounds__(256, 3) void gemm_stage1(
    const float* __restrict__ Xq, const float* __restrict__ Xk, const float* __restrict__ Xv,
    const f16* __restrict__ w16, const float* __restrict__ bperm,
    f16* __restrict__ yq, f16* __restrict__ yk, f16* __restrict__ yv) {
    __shared__ __align__(16) f16 Xs[64 * XSTR];   // 33792 B
    f16* Cb = Xs;                                  // epilogue alias (Xs dead)

    const int z = blockIdx.z;
    const int which = z >> 3;
    const int b = z & 7;
    const float* X = (which == 0) ? Xq : (which == 1) ? Xk : Xv;
    const f16* W = w16 + which * 65536;
    f16* Y = (which == 0) ? yq : (which == 1) ? yk : yv;
    const float* bp = bperm + which * 256;

    const int l0 = blockIdx.x * 64;
    const int tid = threadIdx.x;
    const int wave = tid >> 6, lane = tid & 63;
    const int ln = lane & 15, quad = lane >> 4;
    const int kq = tid & 15;    // chunk-k: k = 64c + 4*kq + r
    const int lg = tid >> 4;    // l: 4*lg + j  (lg 0..15)

    const float* Xbase = X + ((size_t)(b * D_MODEL) + 4 * kq) * SEQL + l0 + 4 * lg;

    float4 xa[4], xb[4];

#define LOADX(DST, C) do { \
        const float* xp_ = Xbase + (size_t)(64 * (C)) * SEQL; \
        DST[0] = *(const float4*)(xp_ + 0 * SEQL); \
        DST[1] = *(const float4*)(xp_ + 1 * SEQL); \
        DST[2] = *(const float4*)(xp_ + 2 * SEQL); \
        DST[3] = *(const float4*)(xp_ + 3 * SEQL); \
    } while (0)

#define STOREB(SRC, C) do { \
        f16x4 w_; \
        w_[0] = (f16)SRC[0].x; w_[1] = (f16)SRC[1].x; w_[2] = (f16)SRC[2].x; w_[3] = (f16)SRC[3].x; \
        *(f16x4*)&Xs[(4 * lg + 0) * XSTR + 64 * (C) + 4 * kq] = w_; \
        w_[0] = (f16)SRC[0].y; w_[1] = (f16)SRC[1].y; w_[2] = (f16)SRC[2].y; w_[3] = (f16)SRC[3].y; \
        *(f16x4*)&Xs[(4 * lg + 1) * XSTR + 64 * (C) + 4 * kq] = w_; \
        w_[0] = (f16)SRC[0].z; w_[1] = (f16)SRC[1].z; w_[2] = (f16)SRC[2].z; w_[3] = (f16)SRC[3].z; \
        *(f16x4*)&Xs[(4 * lg + 2) * XSTR + 64 * (C) + 4 * kq] = w_; \
        w_[0] = (f16)SRC[0].w; w_[1] = (f16)SRC[1].w; w_[2] = (f16)SRC[2].w; w_[3] = (f16)SRC[3].w; \
        *(f16x4*)&Xs[(4 * lg + 3) * XSTR + 64 * (C) + 4 * kq] = w_; \
    } while (0)

    f32x4 acc[4][4];
#pragma unroll
    for (int mf = 0; mf < 4; ++mf)
#pragma unroll
        for (int nf = 0; nf < 4; ++nf)
#pragma unroll
            for (int r = 0; r < 4; ++r) acc[mf][nf][r] = 0.f;

    // staging: 4 chunks of 64 k, 2-deep prefetch, no barriers
    LOADX(xa, 0);
    LOADX(xb, 1);
    STOREB(xa, 0);
    LOADX(xa, 2);
    STOREB(xb, 1);
    LOADX(xb, 3);
    STOREB(xa, 2);
    STOREB(xb, 3);
    __syncthreads();   // the only pre-compute barrier

    // compute: wave owns o-strip wave*64, 8 k-steps, wfrag W loads
    const f16* Wl = W + lane * 8;
    f16x8 afc[4], afn[4];
#pragma unroll
    for (int mf = 0; mf < 4; ++mf)
        afc[mf] = *(const f16x8*)(Wl + (wave * 32 + mf * 8 + 0) * 512);
#pragma unroll
    for (int s = 0; s < 8; ++s) {
        const int k0 = s * 32;
        if (s < 7) {
#pragma unroll
            for (int mf = 0; mf < 4; ++mf)
                afn[mf] = *(const f16x8*)(Wl + (wave * 32 + mf * 8 + s + 1) * 512);
        }
        f16x8 bf[4];
#pragma unroll
        for (int nf = 0; nf < 4; ++nf)
            bf[nf] = *(const f16x8*)&Xs[(nf * 16 + ln) * XSTR + k0 + quad * 8];
#pragma unroll
        for (int mf = 0; mf < 4; ++mf)
#pragma unroll
            for (int nf = 0; nf < 4; ++nf)
                acc[mf][nf] = __builtin_amdgcn_mfma_f32_16x16x32_f16(afc[mf], bf[nf], acc[mf][nf], 0, 0, 0);
#pragma unroll
        for (int mf = 0; mf < 4; ++mf) afc[mf] = afn[mf];
    }

    // epilogue: bias, bounce through Cb as [l][o], coalesced fp16 store
    float bv_[4][4];
#pragma unroll
    for (int mf = 0; mf < 4; ++mf)
#pragma unroll
        for (int r = 0; r < 4; ++r)
            bv_[mf][r] = bp[wave * 64 + mf * 16 + quad * 4 + r];
    __syncthreads();   // all Xs fragment reads complete
#pragma unroll
    for (int mf = 0; mf < 4; ++mf)
#pragma unroll
        for (int nf = 0; nf < 4; ++nf) {
            f16x4 w;
#pragma unroll
            for (int r = 0; r < 4; ++r) w[r] = (f16)(acc[mf][nf][r] + bv_[mf][r]);
            *(f16x4*)&Cb[(nf * 16 + ln) * XSTR + wave * 64 + mf * 16 + quad * 4] = w;
        }
    __syncthreads();
    {
        const int l = tid >> 2, sg = tid & 3;
        f16* yr = Y + ((size_t)(b * SEQL + l0 + l)) * 256 + sg * 64;
#pragma unroll
        for (int u = 0; u < 8; ++u)
            *(f16x8*)(yr + u * 8) = *(const f16x8*)&Cb[l * XSTR + sg * 64 + u * 8];
    }
#undef LOADX
#undef STOREB
}

// ---------------------------------------------------------------------------
// kv_mfma: per (lsplit, b, h) block, KVpart[ls][bh][qd][kd] =
//   sum_{l in split} v'[l][qd] * elu1(k'[l][kd]);  ksum via augmented A-row
//   of ones (vT row 32).  MFMA 16x16x32, LDS-transposed staging, NO atomics.
// (unchanged from round 6 — verified)
// ---------------------------------------------------------------------------
#define KVLP 66
__global__ __launch_bounds__(256) void kv_mfma(
    const f16* __restrict__ kp, const f16* __restrict__ vp,
    float* __restrict__ KVpart, float* __restrict__ ksum_part) {
    __shared__ __align__(16) f16 kT[32 * KVLP];   // [kd][l]  (elu applied)
    __shared__ __align__(16) f16 vT[48 * KVLP];   // [qd][l]; rows 32..47: ones-row aug
    const int ls = blockIdx.x;    // 0..7 (l split of 512)
    const int bh = blockIdx.y;    // 0..63
    const int b = bh >> 3, h = bh & 7;
    const int t = threadIdx.x;
    const int wave = t >> 6, lane = t & 63;
    const int ln = lane & 15, quad = lane >> 4;
    const int lrow = t >> 2, seg = t & 3;

    {
        const int rr = 32 + (t >> 4), c0 = (t & 15) * 4;
        f16x4 w;
        const f16 one = (f16)1.f, zero = (f16)0.f;
        w[0] = w[1] = w[2] = w[3] = (rr == 32) ? one : zero;
        *(f16x4*)&vT[rr * KVLP + c0] = w;
    }

    const int tiP = wave >> 1, tjP = wave & 1;
    f32x4 accP, accS;
#pragma unroll
    for (int r = 0; r < 4; ++r) { accP[r] = 0.f; accS[r] = 0.f; }

    for (int ch = 0; ch < 8; ++ch) {
        __syncthreads();
        const size_t goff = ((size_t)(b * SEQL + ls * 512 + ch * 64 + lrow)) * 256 + h * 32 + seg * 8;
        f16x8 k8 = *(const f16x8*)(kp + goff);
        f16x8 v8 = *(const f16x8*)(vp + goff);
#pragma unroll
        for (int j = 0; j < 8; ++j) {
            kT[(seg * 8 + j) * KVLP + lrow] = (f16)elu1((float)k8[j]);
            vT[(seg * 8 + j) * KVLP + lrow] = v8[j];
        }
        __syncthreads();
#pragma unroll
        for (int ks = 0; ks < 2; ++ks) {
            const int kc = ks * 32 + quad * 8;
            f16x8 bP = *(const f16x8*)&kT[(tjP * 16 + ln) * KVLP + kc];
            f16x8 aP = *(const f16x8*)&vT[(tiP * 16 + ln) * KVLP + kc];
            accP = __builtin_amdgcn_mfma_f32_16x16x32_f16(aP, bP, accP, 0, 0, 0);
            if (wave < 2) {
                f16x8 aS = *(const f16x8*)&vT[(32 + ln) * KVLP + kc];
                accS = __builtin_amdgcn_mfma_f32_16x16x32_f16(aS, bP, accS, 0, 0, 0);
            }
        }
    }

    float* KVp = KVpart + ((size_t)ls * 64 + bh) * 1024;
#pragma unroll
    for (int r = 0; r < 4; ++r)
        KVp[(tiP * 16 + quad * 4 + r) * 32 + tjP * 16 + ln] = accP[r];
    if (wave < 2 && quad == 0)
        ksum_part[((size_t)ls * 64 + bh) * 32 + tjP * 16 + ln] = accS[0];
}

// ---------------------------------------------------------------------------
// kv_reduce: sum the 8 lsplit partials -> final KV [bh][qd][kd], ksum [bh][kd]
// ---------------------------------------------------------------------------
__global__ __launch_bounds__(256) void kv_reduce(
    const float* __restrict__ KVpart, const float* __restrict__ ksum_part,
    float* __restrict__ KVfin, float* __restrict__ ksum_f) {
    const int bh = blockIdx.x;
    const int t = threadIdx.x;
    const float* src = KVpart + (size_t)bh * 1024 + t * 4;
    float ax = 0.f, ay = 0.f, az = 0.f, aw = 0.f;
#pragma unroll
    for (int s = 0; s < 8; ++s) {
        float4 p = *(const float4*)(src + (size_t)s * 65536);
        ax += p.x; ay += p.y; az += p.z; aw += p.w;
    }
    float4 o; o.x = ax; o.y = ay; o.z = az; o.w = aw;
    *(float4*)(KVfin + (size_t)bh * 1024 + t * 4) = o;
    if (t < 32) {
        float ss = 0.f;
#pragma unroll
        for (int s = 0; s < 8; ++s)
            ss += ksum_part[((size_t)s * 64 + bh) * 32 + t];
        ksum_f[bh * 32 + t] = ss;
    }
}

// ---------------------------------------------------------------------------
// Fused attention + output projection.  xs staging now LANE-LINEAR (qp and xs
// are both [l][ch] — no transpose): 8 full lines per wave load instead of 64
// 16B-used lines.  Phase2 Wm reads via wfrag (contiguous 1 KB).
// ---------------------------------------------------------------------------
__global__ __launch_bounds__(256) void attn_out_kernel(
    const f16* __restrict__ qp, const float* __restrict__ KV,
    const float* __restrict__ ksum, const f16* __restrict__ wm16,
    const float* __restrict__ bm, float* __restrict__ out) {
    __shared__ __align__(16) f16 xs[64 * 264];        // 33792 B
    __shared__ __align__(16) f16 Baug[8 * 48 * 40];   // 30720 B
    __shared__ float dens[8][64];                     // 2048 B
    const int b = blockIdx.y;
    const int l0 = blockIdx.x * 64;
    const int t = threadIdx.x;
    const int wave = t >> 6, lane = t & 63;
    const int ln = lane & 15, quad = lane >> 4;

    {
        const int h = t >> 5, qd = t & 31;
        const float* kvp = KV + ((size_t)(b * NHEADS + h) * HDIM + qd) * HDIM;
        f16* dst = &Baug[(h * 48 + qd) * 40];
#pragma unroll
        for (int i = 0; i < 32; i += 4) {
            float4 a = *(const float4*)(kvp + i);
            f16x4 w4;
            w4[0] = (f16)a.x; w4[1] = (f16)a.y; w4[2] = (f16)a.z; w4[3] = (f16)a.w;
            *(f16x4*)(dst + i) = w4;
        }
        Baug[(h * 48 + 32) * 40 + qd] = (f16)ksum[(size_t)(b * NHEADS + h) * HDIM + qd];
    }
    {
        // lane-linear coalesced qp staging: 8 passes x (2 rows x 512 B)/wave
        const int rbase = t >> 5, ch = (t & 31) * 8;
        const f16* qr = qp + ((size_t)(b * SEQL + l0 + rbase)) * 256 + ch;
        f16* dst = &xs[rbase * 264 + ch];
#pragma unroll
        for (int p = 0; p < 8; ++p) {
            f16x8 v = *(const f16x8*)(qr + (size_t)(p * 8) * 256);
            f16x8 w;
#pragma unroll
            for (int j = 0; j < 8; ++j) w[j] = (f16)elu1((float)v[j]);
            *(f16x8*)(dst + p * 8 * 264) = w;
        }
    }
    __syncthreads();
#pragma unroll
    for (int hh = 0; hh < 2; ++hh) {
        const int h = wave * 2 + hh;
        f16x8 a_s[4], b_s[3];
#pragma unroll
        for (int mf = 0; mf < 4; ++mf)
            a_s[mf] = *(const f16x8*)&xs[(mf * 16 + ln) * 264 + h * 32 + quad * 8];
#pragma unroll
        for (int nf = 0; nf < 3; ++nf)
            b_s[nf] = *(const f16x8*)&Baug[(h * 48 + nf * 16 + ln) * 40 + quad * 8];
        f32x4 C[4][3];
#pragma unroll
        for (int mf = 0; mf < 4; ++mf)
#pragma unroll
            for (int nf = 0; nf < 3; ++nf) {
#pragma unroll
                for (int r = 0; r < 4; ++r) C[mf][nf][r] = 0.f;
                C[mf][nf] = __builtin_amdgcn_mfma_f32_16x16x32_f16(a_s[mf], b_s[nf], C[mf][nf], 0, 0, 0);
            }
        if (ln == 0) {
#pragma unroll
            for (int mf = 0; mf < 4; ++mf)
#pragma unroll
                for (int r = 0; r < 4; ++r)
                    dens[h][mf * 16 + quad * 4 + r] = C[mf][2][r];
        }
        __syncthreads();
#pragma unroll
        for (int mf = 0; mf < 4; ++mf)
#pragma unroll
            for (int r = 0; r < 4; ++r) {
                const int l = mf * 16 + quad * 4 + r;
                const float rd = __builtin_amdgcn_rcpf(dens[h][l] + EPS);
#pragma unroll
                for (int nf = 0; nf < 2; ++nf)
                    xs[l * 264 + h * 32 + nf * 16 + ln] = (f16)(C[mf][nf][r] * rd);
            }
        __syncthreads();
    }
    // phase2: main GEMM, A = Wm via wfrag (coalesced), B = xs
    f32x4 acc[4][4];
#pragma unroll
    for (int mf = 0; mf < 4; ++mf)
#pragma unroll
        for (int nf = 0; nf < 4; ++nf)
#pragma unroll
            for (int r = 0; r < 4; ++r) acc[mf][nf][r] = 0.f;
    const f16* Wl = wm16 + lane * 8;
    f16x8 afc[4], afn[4];
#pragma unroll
    for (int mf = 0; mf < 4; ++mf)
        afc[mf] = *(const f16x8*)(Wl + (wave * 32 + mf * 8 + 0) * 512);
#pragma unroll
    for (int it = 0; it < 8; ++it) {
        const int k0 = it * 32;
        if (it < 7) {
#pragma unroll
            for (int mf = 0; mf < 4; ++mf)
                afn[mf] = *(const f16x8*)(Wl + (wave * 32 + mf * 8 + it + 1) * 512);
        }
        f16x8 bf[4];
#pragma unroll
        for (int nf = 0; nf < 4; ++nf)
            bf[nf] = *(const f16x8*)&xs[(nf * 16 + ln) * 264 + k0 + quad * 8];
#pragma unroll
        for (int mf = 0; mf < 4; ++mf)
#pragma unroll
            for (int nf = 0; nf < 4; ++nf)
                acc[mf][nf] = __builtin_amdgcn_mfma_f32_16x16x32_f16(afc[mf], bf[nf], acc[mf][nf], 0, 0, 0);
#pragma unroll
        for (int mf = 0; mf < 4; ++mf) afc[mf] = afn[mf];
    }
#pragma unroll
    for (int mf = 0; mf < 4; ++mf) {
        const int o = wave * 64 + mf * 16 + quad * 4;
#pragma unroll
        for (int r = 0; r < 4; ++r) {
            const float bb = bm[o + r];
            float* op = out + ((size_t)(b * D_MODEL + o + r)) * SEQL + l0;
#pragma unroll
            for (int nf = 0; nf < 4; ++nf)
                op[nf * 16 + ln] = acc[mf][nf][r] + bb;
        }
    }
}

// ---------------------------------------------------------------------------
extern "C" void kernel_launch(void* const* d_in, const int* in_sizes, int n_in,
                              void* d_out, int out_size, void* d_ws, size_t ws_size,
                              hipStream_t stream) {
    const float* query = (const float*)d_in[0];
    const float* key_  = (const float*)d_in[1];
    const float* value = (const float*)d_in[2];
    const float* Wq = (const float*)d_in[3];
    const float* bq = (const float*)d_in[4];
    const float* Wk = (const float*)d_in[5];
    const float* bk = (const float*)d_in[6];
    const float* Wv = (const float*)d_in[7];
    const float* bv = (const float*)d_in[8];
    const float* Wm = (const float*)d_in[9];
    const float* bm = (const float*)d_in[10];

    char* w = (char*)d_ws;
    f16*   w16    = (f16*)w;                        // 524288 B
    float* bperm  = (float*)(w + 524288);           // 3072 B
    float* KVpart = (float*)(w + 528384);           // 2097152 B
    float* ksum_p = (float*)(w + 2625536);          // 65536 B
    float* KVfin  = (float*)(w + 2691072);          // 262144 B
    float* ksum_f = (float*)(w + 2953216);          // 8192 B
    f16*   qp     = (f16*)(w + 2961408);            // 16.7 MB each
    f16*   kp     = qp + (size_t)BATCH * SEQL * 256;
    f16*   vp     = kp + (size_t)BATCH * SEQL * 256;

    prep_kernel<<<1025, 256, 0, stream>>>(Wq, Wk, Wv, Wm, bq, bk, bv, w16, bperm);

    gemm_stage1<<<dim3(SEQL / 64, 1, 24), 256, 0, stream>>>(
        query, key_, value, w16, bperm, qp, kp, vp);

    kv_mfma<<<dim3(8, BATCH * NHEADS), 256, 0, stream>>>(kp, vp, KVpart, ksum_p);

    kv_reduce<<<dim3(BATCH * NHEADS), 256, 0, stream>>>(KVpart, ksum_p, KVfin, ksum_f);

    attn_out_kernel<<<dim3(SEQL / 64, BATCH), 256, 0, stream>>>(
        qp, KVfin, ksum_f, w16 + 3 * 65536, bm, (float*)d_out);
}